// Round 5
// baseline (66.553 us; speedup 1.0000x reference)
//
#include <hip/hip_runtime.h>
#include <cmath>

#define B_ 4
#define N_ 512
#define F_ 128
#define BN_ (B_*N_)   // 2048

__device__ __forceinline__ float elu_f(float x) {
    // elu(x) = max(x, exp(min(x,0))-1): exact for both branches, no cmp/cndmask
    return fmaxf(x, __expf(fminf(x, 0.f)) - 1.f);
}

// ---------------------------------------------------------------------------
// Kernel A: Hi = H @ dW1[:F] + db1 (bias folded), HjT[b][f][n] = (H @ dW1[F:])^T
// 4 rows/block, 256 threads: f = t&127, kh = t>>7 owns a K-half.
// ---------------------------------------------------------------------------
__global__ __launch_bounds__(256) void k_lin1(
    const float* __restrict__ H, const float* __restrict__ dW1,
    const float* __restrict__ db1,
    float* __restrict__ Hi, float* __restrict__ HjT) {
    __shared__ float sH[4][F_];
    __shared__ float sPA[4][F_], sPB[4][F_];
    const int t = threadIdx.x;
    const int f = t & 127;
    const int kh = t >> 7;               // 0/1 K-half
    const int row0 = blockIdx.x * 4;

    #pragma unroll
    for (int p = 0; p < 2; ++p) {
        const int idx = t + p * 256;
        sH[idx >> 7][idx & 127] = H[(size_t)(row0 + (idx >> 7)) * F_ + (idx & 127)];
    }
    __syncthreads();

    float accA[4] = {0.f,0.f,0.f,0.f}, accB[4] = {0.f,0.f,0.f,0.f};
    const int k0 = kh * 64;
    #pragma unroll 4
    for (int k = k0; k < k0 + 64; ++k) {
        const float wa = dW1[(size_t)k * F_ + f];
        const float wb = dW1[(size_t)(F_ + k) * F_ + f];
        #pragma unroll
        for (int r = 0; r < 4; ++r) {
            accA[r] = fmaf(sH[r][k], wa, accA[r]);
            accB[r] = fmaf(sH[r][k], wb, accB[r]);
        }
    }
    if (kh == 1) {
        #pragma unroll
        for (int r = 0; r < 4; ++r) { sPA[r][f] = accA[r]; sPB[r][f] = accB[r]; }
    }
    __syncthreads();
    if (kh == 0) {
        const float bias = db1[f];
        const int b  = row0 >> 9;
        const int n0 = row0 & 511;
        #pragma unroll
        for (int r = 0; r < 4; ++r)
            Hi[(size_t)(row0 + r) * F_ + f] = accA[r] + sPA[r][f] + bias;
        float4 hv;
        hv.x = accB[0] + sPB[0][f];
        hv.y = accB[1] + sPB[1][f];
        hv.z = accB[2] + sPB[2][f];
        hv.w = accB[3] + sPB[3][f];
        *reinterpret_cast<float4*>(HjT + ((size_t)b * F_ + f) * N_ + n0) = hv;
    }
}

// ---------------------------------------------------------------------------
// Kernel B: 4 rows i per block, 512 threads (thread = j). NO LDS in hot loop:
// Hi rows + dW2 read as block-uniform float4 global loads (SMEM/L1 broadcast),
// HjT per-lane coalesced. grid BN/4 = 512 blocks.
// ---------------------------------------------------------------------------
__global__ __launch_bounds__(512) void k_score(
    const float* __restrict__ Hi, const float* __restrict__ HjT,
    const float* __restrict__ A, const float* __restrict__ dW2,
    const float* __restrict__ db2,
    float* __restrict__ maxc, float* __restrict__ degv,
    float* __restrict__ maskout) {
    __shared__ float red_mx[8][4];
    __shared__ int   red_cnt[8][4];
    const int t = threadIdx.x;            // == j
    const int lane = t & 63;
    const int w = t >> 6;                 // wave 0..7
    const int bi0 = blockIdx.x * 4;
    const int b = bi0 >> 9;

    // block-uniform row pointers (blockIdx-derived only -> scalar-load path)
    const float* __restrict__ hi0 = Hi + (size_t)(bi0 + 0) * F_;
    const float* __restrict__ hi1 = Hi + (size_t)(bi0 + 1) * F_;
    const float* __restrict__ hi2 = Hi + (size_t)(bi0 + 2) * F_;
    const float* __restrict__ hi3 = Hi + (size_t)(bi0 + 3) * F_;
    const float* __restrict__ hjp = HjT + (size_t)b * F_ * N_ + t;

    float a_r[4];
    #pragma unroll
    for (int r = 0; r < 4; ++r) a_r[r] = A[(size_t)(bi0 + r) * N_ + t];

    float acc0 = 0.f, acc1 = 0.f, acc2 = 0.f, acc3 = 0.f;
    for (int fq = 0; fq < F_; fq += 4) {
        const float4 h0 = *reinterpret_cast<const float4*>(hi0 + fq);
        const float4 h1 = *reinterpret_cast<const float4*>(hi1 + fq);
        const float4 h2 = *reinterpret_cast<const float4*>(hi2 + fq);
        const float4 h3 = *reinterpret_cast<const float4*>(hi3 + fq);
        const float4 wq = *reinterpret_cast<const float4*>(dW2 + fq);
        const float* h0p = &h0.x; const float* h1p = &h1.x;
        const float* h2p = &h2.x; const float* h3p = &h3.x;
        const float* wqp = &wq.x;
        #pragma unroll
        for (int s = 0; s < 4; ++s) {
            const float hj = hjp[(size_t)(fq + s) * N_];
            const float wv = wqp[s];
            acc0 = fmaf(elu_f(h0p[s] + hj), wv, acc0);
            acc1 = fmaf(elu_f(h1p[s] + hj), wv, acc1);
            acc2 = fmaf(elu_f(h2p[s] + hj), wv, acc2);
            acc3 = fmaf(elu_f(h3p[s] + hj), wv, acc3);
        }
    }

    float accv[4] = {acc0, acc1, acc2, acc3};
    #pragma unroll
    for (int r = 0; r < 4; ++r) {
        float mx = (a_r[r] > 0.1f) ? accv[r] : -INFINITY;
        int cnt = (a_r[r] > 0.f) ? 1 : 0;
        #pragma unroll
        for (int off = 1; off < 64; off <<= 1) {
            mx = fmaxf(mx, __shfl_xor(mx, off));
            cnt += __shfl_xor(cnt, off);
        }
        if (lane == 0) { red_mx[w][r] = mx; red_cnt[w][r] = cnt; }
    }
    __syncthreads();
    if (t < 4) {
        float m = -INFINITY; int c = 0;
        #pragma unroll
        for (int ww = 0; ww < 8; ++ww) {
            m = fmaxf(m, red_mx[ww][t]);
            c += red_cnt[ww][t];
        }
        const float mc = (m > -INFINITY)
                       ? 1.f / (1.f + __expf(-(m + db2[0]))) : 0.f;
        maxc[bi0 + t] = mc;
        degv[bi0 + t] = (float)c;
        maskout[bi0 + t] = (mc > 0.5f) ? 1.f : 0.f;
    }
}

// ---------------------------------------------------------------------------
// Kernel N: neighbor mean. 4 rows/block, 256 threads = 4 waves; wave w owns
// j-range [w*128, w*128+128). Mask held as ballot bits in SGPRs; bit-test ->
// uniform 0/1 float -> fma with SGPR operand. float2 H loads (f = 2*lane).
// ---------------------------------------------------------------------------
__global__ __launch_bounds__(256) void k_nbr(
    const float* __restrict__ A, const float* __restrict__ H,
    const float* __restrict__ degv, float* __restrict__ nf) {
    __shared__ float2 sPart[4][4][64];
    const int t = threadIdx.x;
    const int lane = t & 63;
    const int w = t >> 6;                 // wave 0..3
    const int bi0 = blockIdx.x * 4;
    const int b = bi0 >> 9;

    unsigned long long msk[2][4];
    #pragma unroll
    for (int sub = 0; sub < 2; ++sub) {
        const int jj = w * 128 + sub * 64 + lane;
        #pragma unroll
        for (int r = 0; r < 4; ++r)
            msk[sub][r] = __ballot(A[(size_t)(bi0 + r) * N_ + jj] > 0.f);
    }

    float2 acc[4];
    #pragma unroll
    for (int r = 0; r < 4; ++r) acc[r] = make_float2(0.f, 0.f);

    const float* hb = H + ((size_t)b * N_ + w * 128) * F_ + 2 * lane;
    #pragma unroll
    for (int sub = 0; sub < 2; ++sub) {
        #pragma unroll 8
        for (int j = 0; j < 64; ++j) {
            const float2 h2 = *reinterpret_cast<const float2*>(
                hb + (size_t)(sub * 64 + j) * F_);
            #pragma unroll
            for (int r = 0; r < 4; ++r) {
                const float m = ((msk[sub][r] >> j) & 1ull) ? 1.f : 0.f;
                acc[r].x = fmaf(m, h2.x, acc[r].x);
                acc[r].y = fmaf(m, h2.y, acc[r].y);
            }
        }
    }
    #pragma unroll
    for (int r = 0; r < 4; ++r) sPart[w][r][lane] = acc[r];
    __syncthreads();
    if (w == 0) {
        #pragma unroll
        for (int r = 0; r < 4; ++r) {
            float2 s = sPart[0][r][lane];
            #pragma unroll
            for (int ww = 1; ww < 4; ++ww) {
                s.x += sPart[ww][r][lane].x;
                s.y += sPart[ww][r][lane].y;
            }
            const float d = fmaxf(degv[bi0 + r], 1.f);
            float2 o; o.x = s.x / d; o.y = s.y / d;
            *reinterpret_cast<float2*>(nf + (size_t)(bi0 + r) * F_ + 2 * lane) = o;
        }
    }
}

// ---------------------------------------------------------------------------
// Kernel C: res = elu([H,nf,maxc] @ rW1 + rb1) @ rW2 + rb2; select per row.
// 4 rows/block, 512 blocks, 512 threads: f = t&127, kq = t>>7 K-quarter.
// Layer-1 inputs read from GLOBAL via uniform float4 (no sC staging).
// ---------------------------------------------------------------------------
__global__ __launch_bounds__(512) void k_mlp(
    const float* __restrict__ H, const float* __restrict__ nf,
    const float* __restrict__ maxc, const float* __restrict__ degv,
    const float* __restrict__ rW1, const float* __restrict__ rb1,
    const float* __restrict__ rW2, const float* __restrict__ rb2,
    float* __restrict__ out) {
    __shared__ float sP[3][4][F_];
    __shared__ float sL1[4][F_];
    const int t  = threadIdx.x;
    const int f  = t & 127;
    const int kq = t >> 7;                // 0..3
    const int row0 = blockIdx.x * 4;

    // ---- layer 1: quarters 0,1 read H cols [kq*64 ..], 2,3 read nf ----
    const float* __restrict__ srcbase = (kq < 2) ? H : nf;
    const int koff = (kq < 2) ? (kq * 64) : (kq * 64 - 128);
    const float* __restrict__ s0 = srcbase + (size_t)(row0 + 0) * F_ + koff;
    const float* __restrict__ s1 = srcbase + (size_t)(row0 + 1) * F_ + koff;
    const float* __restrict__ s2 = srcbase + (size_t)(row0 + 2) * F_ + koff;
    const float* __restrict__ s3 = srcbase + (size_t)(row0 + 3) * F_ + koff;

    float acc[4];
    {
        const float bias = rb1[f];
        #pragma unroll
        for (int r = 0; r < 4; ++r) acc[r] = (kq == 0) ? bias : 0.f;
    }
    const int kg0 = kq * 64;
    for (int kk = 0; kk < 64; kk += 4) {
        const float4 c0 = *reinterpret_cast<const float4*>(s0 + kk);
        const float4 c1 = *reinterpret_cast<const float4*>(s1 + kk);
        const float4 c2 = *reinterpret_cast<const float4*>(s2 + kk);
        const float4 c3 = *reinterpret_cast<const float4*>(s3 + kk);
        const float* c0p = &c0.x; const float* c1p = &c1.x;
        const float* c2p = &c2.x; const float* c3p = &c3.x;
        #pragma unroll
        for (int s = 0; s < 4; ++s) {
            const float wv = rW1[(size_t)(kg0 + kk + s) * F_ + f];
            acc[0] = fmaf(c0p[s], wv, acc[0]);
            acc[1] = fmaf(c1p[s], wv, acc[1]);
            acc[2] = fmaf(c2p[s], wv, acc[2]);
            acc[3] = fmaf(c3p[s], wv, acc[3]);
        }
    }
    if (kq == 3) {                        // k = 256: maxc column
        const float w256 = rW1[(size_t)256 * F_ + f];
        #pragma unroll
        for (int r = 0; r < 4; ++r)
            acc[r] = fmaf(maxc[row0 + r], w256, acc[r]);
    }
    if (kq > 0) {
        #pragma unroll
        for (int r = 0; r < 4; ++r) sP[kq - 1][r][f] = acc[r];
    }
    __syncthreads();
    if (kq == 0) {
        #pragma unroll
        for (int r = 0; r < 4; ++r)
            sL1[r][f] = elu_f(acc[r] + sP[0][r][f] + sP[1][r][f] + sP[2][r][f]);
    }
    __syncthreads();

    // ---- layer 2: each kq handles its own 32-k slice of sL1 ----
    float acc2[4];
    {
        const float bias2 = rb2[f];
        #pragma unroll
        for (int r = 0; r < 4; ++r) acc2[r] = (kq == 0) ? bias2 : 0.f;
    }
    const int m0k = kq * 32;
    for (int kk = 0; kk < 32; kk += 4) {
        const float4 l0 = *reinterpret_cast<const float4*>(&sL1[0][m0k + kk]);
        const float4 l1 = *reinterpret_cast<const float4*>(&sL1[1][m0k + kk]);
        const float4 l2 = *reinterpret_cast<const float4*>(&sL1[2][m0k + kk]);
        const float4 l3 = *reinterpret_cast<const float4*>(&sL1[3][m0k + kk]);
        const float* l0p = &l0.x; const float* l1p = &l1.x;
        const float* l2p = &l2.x; const float* l3p = &l3.x;
        #pragma unroll
        for (int s = 0; s < 4; ++s) {
            const float wv = rW2[(size_t)(m0k + kk + s) * F_ + f];
            acc2[0] = fmaf(l0p[s], wv, acc2[0]);
            acc2[1] = fmaf(l1p[s], wv, acc2[1]);
            acc2[2] = fmaf(l2p[s], wv, acc2[2]);
            acc2[3] = fmaf(l3p[s], wv, acc2[3]);
        }
    }
    if (kq > 0) {
        #pragma unroll
        for (int r = 0; r < 4; ++r) sP[kq - 1][r][f] = acc2[r];
    }
    __syncthreads();
    if (kq == 0) {
        #pragma unroll
        for (int r = 0; r < 4; ++r) {
            const int row = row0 + r;
            const float res = acc2[r] + sP[0][r][f] + sP[1][r][f] + sP[2][r][f];
            const bool upd = (maxc[row] > 0.5f) && (degv[row] > 0.f);
            out[(size_t)row * F_ + f] = upd ? res : H[(size_t)row * F_ + f];
        }
    }
}

// ---------------------------------------------------------------------------
extern "C" void kernel_launch(void* const* d_in, const int* in_sizes, int n_in,
                              void* d_out, int out_size, void* d_ws, size_t ws_size,
                              hipStream_t stream) {
    const float* H   = (const float*)d_in[0];
    const float* A   = (const float*)d_in[1];
    const float* dW1 = (const float*)d_in[2];
    const float* db1 = (const float*)d_in[3];
    const float* dW2 = (const float*)d_in[4];
    const float* db2 = (const float*)d_in[5];
    const float* rW1 = (const float*)d_in[6];
    const float* rb1 = (const float*)d_in[7];
    const float* rW2 = (const float*)d_in[8];
    const float* rb2 = (const float*)d_in[9];

    float* ws   = (float*)d_ws;
    float* Hi   = ws;                      // [BN][F]
    float* HjT  = Hi + BN_ * F_;           // [B][F][N]
    float* maxc = HjT + BN_ * F_;          // [BN]
    float* degv = maxc + BN_;              // [BN]
    float* nf   = degv + BN_;              // [BN][F]

    float* out      = (float*)d_out;       // [BN][F] H_resolved
    float* mask_out = out + BN_ * F_;      // [BN] contra_mask as 0/1

    k_lin1 <<<BN_ / 4, 256, 0, stream>>>(H, dW1, db1, Hi, HjT);
    k_score<<<BN_ / 4, 512, 0, stream>>>(Hi, HjT, A, dW2, db2, maxc, degv, mask_out);
    k_nbr  <<<BN_ / 4, 256, 0, stream>>>(A, H, degv, nf);
    k_mlp  <<<BN_ / 4, 512, 0, stream>>>(H, nf, maxc, degv, rW1, rb1, rW2, rb2, out);
}